// Round 2
// baseline (1386.066 us; speedup 1.0000x reference)
//
#include <hip/hip_runtime.h>

// B=32, S=128, D=300 (pad 320), VOCAB=20000 (625 chunks of 32), K=8.
// Inputs may be f32 or bf16 (runtime-detected); canonicalized to bf16 in ws.

typedef unsigned short u16;
typedef unsigned int   u32;
typedef float  f32x4 __attribute__((ext_vector_type(4)));
typedef u32    u32x4 __attribute__((ext_vector_type(4)));
typedef __bf16 bf16x8 __attribute__((ext_vector_type(8)));
typedef _Float16 f16x2 __attribute__((ext_vector_type(2)));

__device__ __forceinline__ float bf2f(u16 u) { return __uint_as_float(((u32)u) << 16); }
__device__ __forceinline__ u16 f2bf(float f) {
  u32 x = __float_as_uint(f);
  u32 r = (x + 0x7fffu + ((x >> 16) & 1u)) >> 16;  // RNE
  return (u16)r;
}
__device__ __forceinline__ float sigm(float x) { return 1.f / (1.f + __expf(-x)); }

__device__ __forceinline__ float dot2f(f16x2 a, f16x2 b, float c) {
#if defined(__has_builtin) && __has_builtin(__builtin_amdgcn_fdot2)
  return __builtin_amdgcn_fdot2(a, b, c, false);
#else
  return c + (float)a[0] * (float)b[0] + (float)a[1] * (float)b[1];
#endif
}

__device__ __forceinline__ f32x4 shflx4(f32x4 v, int m) {
  f32x4 r;
  r[0] = __shfl_xor(v[0], m, 16);
  r[1] = __shfl_xor(v[1], m, 16);
  r[2] = __shfl_xor(v[2], m, 16);
  r[3] = __shfl_xor(v[3], m, 16);
  return r;
}

// ---------- ingest: detect f32 vs bf16, canonicalize all float inputs to bf16 ----------
__device__ __forceinline__ void conv_seg(const void* src, u16* dst, int n, int is32,
                                         int t0, int stride) {
  if (is32) {
    const float* s = (const float*)src;
    for (int i = t0; i < n; i += stride) dst[i] = f2bf(s[i]);
  } else {
    const u16* s = (const u16*)src;
    for (int i = t0; i < n; i += stride) dst[i] = s[i];
  }
}

__global__ __launch_bounds__(256) void k_ingest(
    const void* words, const void* vocab, const void* de, const void* W,
    const void* lWih, const void* lWhh, const void* lbih, const void* lbhh,
    const void* rWih, const void* rWhh, const void* rbih, const void* rbhh,
    u16* cw, u16* cv, u16* cde, u16* cW, u16* cWih, u16* cWhh, u16* cbih, u16* cbhh,
    u16* crWih, u16* crWhh, u16* crbih, u16* crbhh, u32* flag) {
  __shared__ int s_is32;
  int tid = threadIdx.x;
  int vote = 0;
  if (tid < 64) {
    u32 w = ((const u32*)words)[tid];
    int e = (w >> 7) & 0xFF;  // bf16 low-element exponent field if bf16-packed
    vote = (e >= 100 && e <= 150) ? 1 : 0;
  }
  unsigned long long m = __ballot(vote);
  if (tid == 0) s_is32 = (__popcll(m) < 32) ? 1 : 0;  // few plausible bf16 exps -> f32
  __syncthreads();
  int is32 = s_is32;
  if (blockIdx.x == 0 && tid == 0) *flag = (u32)is32;
  int t0 = blockIdx.x * 256 + tid;
  int stride = gridDim.x * 256;
  conv_seg(words, cw, 1228800, is32, t0, stride);
  conv_seg(vocab, cv, 6000000, is32, t0, stride);
  conv_seg(de, cde, 300, is32, t0, stride);
  conv_seg(W, cW, 90000, is32, t0, stride);
  conv_seg(lWih, cWih, 360000, is32, t0, stride);
  conv_seg(lWhh, cWhh, 360000, is32, t0, stride);
  conv_seg(lbih, cbih, 1200, is32, t0, stride);
  conv_seg(lbhh, cbhh, 1200, is32, t0, stride);
  conv_seg(rWih, crWih, 90000, is32, t0, stride);
  conv_seg(rWhh, crWhh, 90000, is32, t0, stride);
  conv_seg(rbih, crbih, 300, is32, t0, stride);
  conv_seg(rbhh, crbhh, 300, is32, t0, stride);
}

// ---------- transpose bf16 (J x K) -> bf16 (K x J) ----------
__global__ __launch_bounds__(256) void k_transpose_bf(const u16* __restrict__ in,
                                                      u16* __restrict__ out,
                                                      int J, int K) {
  __shared__ u16 t[32][33];
  int j0 = blockIdx.x * 32, k0 = blockIdx.y * 32;
  int lx = threadIdx.x & 31, ly = threadIdx.x >> 5;
  for (int r = ly; r < 32; r += 8) {
    int j = j0 + r, k = k0 + lx;
    t[r][lx] = (j < J && k < K) ? in[(size_t)j * K + k] : (u16)0;
  }
  __syncthreads();
  for (int r = ly; r < 32; r += 8) {
    int k = k0 + r, j = j0 + lx;
    if (k < K && j < J) out[(size_t)k * J + j] = t[lx][r];
  }
}

// ---------- pack lstm_Whh (1200x300 bf16) -> half2 pairs W2[kp=150][j=1200] ----------
__global__ __launch_bounds__(256) void k_pack_whh(const u16* __restrict__ Whh,
                                                  u32* __restrict__ W2) {
  int idx = blockIdx.x * 256 + threadIdx.x;
  if (idx >= 150 * 1200) return;
  int kp = idx / 1200, j = idx - kp * 1200;
  float a = bf2f(Whh[(size_t)j * 300 + 2 * kp]);
  float b = bf2f(Whh[(size_t)j * 300 + 2 * kp + 1]);
  union { f16x2 v; u32 u; } cvv;
  cvv.v[0] = (_Float16)a; cvv.v[1] = (_Float16)b;
  W2[idx] = cvv.u;
}

// ---------- pack vocab into MFMA operand layouts ----------
__global__ __launch_bounds__(256) void k_pack_vocab(const u16* __restrict__ vocab,
                                                    u16* __restrict__ pA,
                                                    u16* __restrict__ pB) {
  __shared__ u16 sv[32][320];
  int ci = blockIdx.x, tid = threadIdx.x;
  for (int idx = tid; idx < 32 * 20; idx += 256) {
    int v = idx / 20, k = 300 + (idx - v * 20);
    sv[v][k] = 0;
  }
  for (int idx = tid; idx < 32 * 300; idx += 256) {
    int v = idx / 300, k = idx - v * 300;
    sv[v][k] = vocab[(size_t)(ci * 32 + v) * 300 + k];
  }
  __syncthreads();
  for (int idx = tid; idx < 10240; idx += 256) {
    int j = idx & 7, lane = (idx >> 3) & 63, t2 = idx >> 9;
    int kk = t2 % 10, h = t2 / 10;
    int v = h * 16 + (lane & 15);
    int k = kk * 32 + ((lane >> 4)) * 8 + j;
    pA[(size_t)ci * 10240 + (size_t)idx] = sv[v][k];
  }
  for (int idx = tid; idx < 9728; idx += 256) {
    int j = idx & 7, lane = (idx >> 3) & 63, nc = idx >> 9;
    int v = (lane >> 4) * 8 + j;
    int n = nc * 16 + (lane & 15);
    pB[(size_t)ci * 9728 + (size_t)idx] = sv[v][n];
  }
}

// ---------- X = words @ W -> bf16 (4096 x 320, zero pad) ----------
__global__ __launch_bounds__(256) void k_xw(const u16* __restrict__ words,
                                            const u16* __restrict__ W,
                                            u16* __restrict__ X) {
  __shared__ float As[300][33];
  int n0 = blockIdx.x * 128;
  int r0 = blockIdx.y * 32;
  int tid = threadIdx.x;
  for (int idx = tid; idx < 32 * 300; idx += 256) {
    int r = idx / 300, k = idx - r * 300;
    As[k][r] = bf2f(words[(size_t)(r0 + r) * 300 + k]);
  }
  __syncthreads();
  int j = n0 + (tid & 127);
  int rh = (tid >> 7) * 16;
  float acc[16];
#pragma unroll
  for (int i = 0; i < 16; i++) acc[i] = 0.f;
  if (j < 300) {
    for (int k = 0; k < 300; k++) {
      float bw = bf2f(W[(size_t)k * 300 + j]);
#pragma unroll
      for (int i = 0; i < 16; i++) acc[i] += As[k][rh + i] * bw;
    }
  }
  if (j < 320) {
#pragma unroll
    for (int i = 0; i < 16; i++) {
      float v = (j < 300) ? acc[i] : 0.f;
      X[(size_t)(r0 + rh + i) * 320 + j] = f2bf(v);
    }
  }
}

// ---------- flash-style softmax-weighted vocab sum (MFMA), per-slice partials ----------
__global__ __launch_bounds__(512, 2) void k_softmax_v(
    const u16* __restrict__ X, const u16* __restrict__ pA, const u16* __restrict__ pB,
    u16* __restrict__ pAcc, float* __restrict__ pML) {
  __shared__ __align__(16) u16 chunk[19968];
  __shared__ __align__(16) float ptbuf[8 * 576];
  int bid = blockIdx.x;
  int sl = bid & 7, b = bid >> 3;
  int tid = threadIdx.x;
  int w = tid >> 6, lane = tid & 63;
  int quad = lane >> 4, n16 = lane & 15;
  int cs = (sl == 0) ? 0 : 79 + (sl - 1) * 78;
  int nch = (sl == 0) ? 79 : 78;

  int rowA = b * 128 + w * 16 + n16;
  const bf16x8* Xrow = (const bf16x8*)(X + (size_t)rowA * 320);
  bf16x8 afr[10];
#pragma unroll
  for (int kk = 0; kk < 10; kk++) afr[kk] = Xrow[kk * 4 + quad];

  f32x4 acc[19];
#pragma unroll
  for (int i = 0; i < 19; i++) { acc[i][0] = 0.f; acc[i][1] = 0.f; acc[i][2] = 0.f; acc[i][3] = 0.f; }
  f32x4 mrun, lrun;
#pragma unroll
  for (int c = 0; c < 4; c++) { mrun[c] = -1e30f; lrun[c] = 0.f; }
  float* myPt = ptbuf + w * 576;

  {
    const u32x4* gA = (const u32x4*)pA + (size_t)cs * 1280;
    const u32x4* gB = (const u32x4*)pB + (size_t)cs * 1216;
    u32x4* sb = (u32x4*)&chunk[0];
    for (int idx = tid; idx < 2496; idx += 512)
      sb[idx] = (idx < 1280) ? gA[idx] : gB[idx - 1280];
  }
  __syncthreads();

  for (int ic = 0; ic < nch; ic++) {
    u32x4 pf[5];
    bool havepf = (ic + 1 < nch);
    if (havepf) {
      int ci = cs + ic + 1;
      const u32x4* gA = (const u32x4*)pA + (size_t)ci * 1280;
      const u32x4* gB = (const u32x4*)pB + (size_t)ci * 1216;
#pragma unroll
      for (int i = 0; i < 5; i++) {
        int idx = tid + i * 512;
        if (idx < 2496) pf[i] = (idx < 1280) ? gA[idx] : gB[idx - 1280];
      }
    }
    const bf16x8* bufA = (const bf16x8*)&chunk[0];
    const bf16x8* bufB = (const bf16x8*)&chunk[10240];
    f32x4 L0, L1;
#pragma unroll
    for (int c = 0; c < 4; c++) { L0[c] = 0.f; L1[c] = 0.f; }
#pragma unroll
    for (int kk = 0; kk < 10; kk++) {
      L0 = __builtin_amdgcn_mfma_f32_16x16x32_bf16(afr[kk], bufA[kk * 64 + lane], L0, 0, 0, 0);
      L1 = __builtin_amdgcn_mfma_f32_16x16x32_bf16(afr[kk], bufA[(10 + kk) * 64 + lane], L1, 0, 0, 0);
    }
    f32x4 t;
#pragma unroll
    for (int c = 0; c < 4; c++) t[c] = fmaxf(L0[c], L1[c]);
#pragma unroll
    for (int off = 1; off < 16; off <<= 1) {
      f32x4 o = shflx4(t, off);
#pragma unroll
      for (int c = 0; c < 4; c++) t[c] = fmaxf(t[c], o[c]);
    }
    f32x4 mnew, al, P0v, P1v, rs;
#pragma unroll
    for (int c = 0; c < 4; c++) {
      mnew[c] = fmaxf(mrun[c], t[c]);
      al[c] = __expf(mrun[c] - mnew[c]);
      P0v[c] = __expf(L0[c] - mnew[c]);
      P1v[c] = __expf(L1[c] - mnew[c]);
      rs[c] = P0v[c] + P1v[c];
    }
#pragma unroll
    for (int off = 1; off < 16; off <<= 1) {
      f32x4 o = shflx4(rs, off);
#pragma unroll
      for (int c = 0; c < 4; c++) rs[c] += o[c];
    }
#pragma unroll
    for (int c = 0; c < 4; c++) { lrun[c] = lrun[c] * al[c] + rs[c]; mrun[c] = mnew[c]; }
#pragma unroll
    for (int r = 0; r < 4; r++) {
      myPt[(quad * 4 + r) * 36 + n16] = P0v[r];
      myPt[(quad * 4 + r) * 36 + 16 + n16] = P1v[r];
    }
    __syncthreads();  // harden LDS write->read ordering for the P transpose
    f32x4 plo = *(const f32x4*)(myPt + n16 * 36 + quad * 8);
    f32x4 phi = *(const f32x4*)(myPt + n16 * 36 + quad * 8 + 4);
    bf16x8 paf;
#pragma unroll
    for (int c = 0; c < 4; c++) { paf[c] = (__bf16)plo[c]; paf[c + 4] = (__bf16)phi[c]; }
#pragma unroll
    for (int nc = 0; nc < 19; nc++) {
      f32x4 a = acc[nc];
#pragma unroll
      for (int c = 0; c < 4; c++) a[c] *= al[c];
      acc[nc] = __builtin_amdgcn_mfma_f32_16x16x32_bf16(paf, bufB[nc * 64 + lane], a, 0, 0, 0);
    }
    __syncthreads();  // all reads of chunk done
    if (havepf) {
      u32x4* sb = (u32x4*)&chunk[0];
#pragma unroll
      for (int i = 0; i < 5; i++) {
        int idx = tid + i * 512;
        if (idx < 2496) sb[idx] = pf[i];
      }
    }
    __syncthreads();  // chunk ready
  }

  size_t prow = (size_t)sl * 4096 + (size_t)b * 128 + w * 16;
  if (n16 == 0) {
#pragma unroll
    for (int r = 0; r < 4; r++) {
      pML[(prow + quad * 4 + r) * 2 + 0] = mrun[r];
      pML[(prow + quad * 4 + r) * 2 + 1] = lrun[r];
    }
  }
#pragma unroll
  for (int nc = 0; nc < 19; nc++)
#pragma unroll
    for (int r = 0; r < 4; r++)
      pAcc[(prow + quad * 4 + r) * 304 + nc * 16 + n16] = f2bf(acc[nc][r]);
}

// ---------- combine slices + default-embed column -> V bf16 (4096 x 320) ----------
__global__ __launch_bounds__(320) void k_combine(
    const u16* __restrict__ pAcc, const float* __restrict__ pML,
    const u16* __restrict__ X, const u16* __restrict__ de,
    const u16* __restrict__ words, u16* __restrict__ Vout) {
  __shared__ float red[320];
  __shared__ float fs[8];
  __shared__ float sinv, sw;
  int row = blockIdx.x, tid = threadIdx.x;
  float p = 0.f;
  if (tid < 300) p = bf2f(X[(size_t)row * 320 + tid]) * bf2f(de[tid]);
  red[tid] = p;
  __syncthreads();
  if (tid == 0) {
    float d = 0.f;
    for (int i = 0; i < 300; i++) d += red[i];
    float mv[8], lv[8], ms = -1e30f;
    for (int s = 0; s < 8; s++) {
      mv[s] = pML[((size_t)s * 4096 + row) * 2];
      lv[s] = pML[((size_t)s * 4096 + row) * 2 + 1];
      ms = fmaxf(ms, mv[s]);
    }
    float mf = fmaxf(ms, d);
    float pd = __expf(d - mf);
    float l = pd;
    for (int s = 0; s < 8; s++) {
      float f = __expf(mv[s] - mf);
      fs[s] = f;
      l += lv[s] * f;
    }
    sinv = 1.f / l;
    sw = pd / l;
  }
  __syncthreads();
  float v = 0.f;
  if (tid < 300) {
    float a = 0.f;
#pragma unroll
    for (int s = 0; s < 8; s++)
      a += bf2f(pAcc[((size_t)s * 4096 + row) * 304 + tid]) * fs[s];
    v = a * sinv + sw * bf2f(words[(size_t)row * 300 + tid]);
  }
  Vout[(size_t)row * 320 + tid] = f2bf(v);
}

// ---------- xg = V @ lstm_Wih.T + bih + bhh (f32, 4096 x 1200) ----------
__global__ __launch_bounds__(256) void k_xg(const u16* __restrict__ Vb,
                                            const u16* __restrict__ WihT,
                                            const u16* __restrict__ bih,
                                            const u16* __restrict__ bhh,
                                            float* __restrict__ xg) {
  __shared__ float As[300][33];
  int n0 = blockIdx.x * 128;
  int r0 = blockIdx.y * 32;
  int tid = threadIdx.x;
  for (int idx = tid; idx < 32 * 300; idx += 256) {
    int r = idx / 300, k = idx - r * 300;
    As[k][r] = bf2f(Vb[(size_t)(r0 + r) * 320 + k]);
  }
  __syncthreads();
  int j = n0 + (tid & 127);
  if (j >= 1200) return;
  int rh = (tid >> 7) * 16;
  float acc[16];
#pragma unroll
  for (int i = 0; i < 16; i++) acc[i] = 0.f;
  for (int k = 0; k < 300; k++) {
    float bw = bf2f(WihT[(size_t)k * 1200 + j]);
#pragma unroll
    for (int i = 0; i < 16; i++) acc[i] += As[k][rh + i] * bw;
  }
  float bias = bf2f(bih[j]) + bf2f(bhh[j]);
#pragma unroll
  for (int i = 0; i < 16; i++)
    xg[(size_t)(r0 + rh + i) * 1200 + j] = acc[i] + bias;
}

// ---------- sequential LSTM + 8-step RNN, one block per batch ----------
__global__ __launch_bounds__(640) void k_lstm_rnn(
    const float* __restrict__ xg, const u32* __restrict__ W2,
    const u16* __restrict__ rWihT, const u16* __restrict__ rWhhT,
    const u16* __restrict__ rbih, const u16* __restrict__ rbhh,
    const int* __restrict__ lengths, float* __restrict__ H) {
  __shared__ __align__(16) float hs[304];
  __shared__ __align__(16) float cs_[304];
  __shared__ __align__(4) u16 hsh[304];
  __shared__ __align__(16) float ps[2][1200];
  __shared__ __align__(16) float gs[1200];
  __shared__ __align__(16) float h2[304];
  __shared__ __align__(16) float base[304];
  int b = blockIdx.x, tid = threadIdx.x;
  int len = lengths[b];
  if (tid < 304) { hs[tid] = 0.f; cs_[tid] = 0.f; hsh[tid] = 0; }
  __syncthreads();
  int g = tid % 300;
  int kq = tid / 300;
  for (int t = 0; t < len; t++) {
    if (tid < 600) {
      int j4 = g * 4;
      float a0 = 0.f, a1 = 0.f, a2 = 0.f, a3 = 0.f;
      const u32* wp = W2 + (size_t)(kq * 75) * 1200 + j4;
      const u32* hp = (const u32*)hsh + kq * 75;
#pragma unroll 5
      for (int kp = 0; kp < 75; kp++) {
        union { u32 u; f16x2 v; } hh; hh.u = hp[kp];
        u32x4 wv = *(const u32x4*)(wp + (size_t)kp * 1200);
        union { u32 u; f16x2 v; } w0, w1, w2, w3;
        w0.u = wv[0]; w1.u = wv[1]; w2.u = wv[2]; w3.u = wv[3];
        a0 = dot2f(hh.v, w0.v, a0);
        a1 = dot2f(hh.v, w1.v, a1);
        a2 = dot2f(hh.v, w2.v, a2);
        a3 = dot2f(hh.v, w3.v, a3);
      }
      f32x4 av; av[0] = a0; av[1] = a1; av[2] = a2; av[3] = a3;
      *(f32x4*)&ps[kq][j4] = av;
    }
    __syncthreads();
    if (tid < 300) {
      int j4 = tid * 4;
      const float* xr = xg + (size_t)(b * 128 + t) * 1200 + j4;
      f32x4 p0 = *(const f32x4*)&ps[0][j4];
      f32x4 p1 = *(const f32x4*)&ps[1][j4];
      f32x4 xv = *(const f32x4*)xr;
      f32x4 gv;
#pragma unroll
      for (int c = 0; c < 4; c++) gv[c] = xv[c] + p0[c] + p1[c];
      *(f32x4*)&gs[j4] = gv;
    }
    __syncthreads();
    if (tid < 300) {
      float ig = gs[tid], fg = gs[300 + tid], gg = gs[600 + tid], og = gs[900 + tid];
      float c = sigm(fg) * cs_[tid] + sigm(ig) * tanhf(gg);
      float h = sigm(og) * tanhf(c);
      cs_[tid] = c; hs[tid] = h;
      union { _Float16 h; u16 u; } cvv; cvv.h = (_Float16)h;
      hsh[tid] = cvv.u;
    }
    __syncthreads();
  }
  if (tid < 300) {
    float a = bf2f(rbih[tid]) + bf2f(rbhh[tid]);
    for (int k = 0; k < 300; k++) a += hs[k] * bf2f(rWihT[(size_t)k * 300 + tid]);
    base[tid] = a;
  }
  if (tid < 304) h2[tid] = 0.f;
  __syncthreads();
  for (int s = 0; s < 8; s++) {
    float nv = 0.f;
    if (tid < 300) {
      float a = base[tid];
      for (int k = 0; k < 300; k++) a += h2[k] * bf2f(rWhhT[(size_t)k * 300 + tid]);
      nv = tanhf(a);
    }
    __syncthreads();
    if (tid < 300) {
      h2[tid] = nv;
      H[((size_t)b * 8 + s) * 300 + tid] = nv;
    }
    __syncthreads();
  }
}

// ---------- attention readout ----------
__global__ __launch_bounds__(256) void k_attn(const float* __restrict__ H,
                                              const u16* __restrict__ Vb,
                                              const int* __restrict__ lengths,
                                              const u32* __restrict__ flag,
                                              void* __restrict__ dout) {
  __shared__ float Hs[8][304];
  __shared__ float sc[8][128];
  __shared__ float wsum[8];
  int b = blockIdx.x, tid = threadIdx.x;
  int len = lengths[b];
  int is32 = (int)*flag;
  for (int idx = tid; idx < 8 * 300; idx += 256) {
    int k = idx / 300, j = idx - k * 300;
    Hs[k][j] = H[((size_t)b * 8 + k) * 300 + j];
  }
  __syncthreads();
  for (int s = tid; s < len; s += 256) {
    const u16* vr = Vb + (size_t)(b * 128 + s) * 320;
    float a[8];
#pragma unroll
    for (int k = 0; k < 8; k++) a[k] = 0.f;
    for (int j = 0; j < 300; j++) {
      float v = bf2f(vr[j]);
#pragma unroll
      for (int k = 0; k < 8; k++) a[k] += Hs[k][j] * v;
    }
#pragma unroll
    for (int k = 0; k < 8; k++) sc[k][s] = a[k];
  }
  __syncthreads();
  if (tid < 8) {
    float m = -1e30f;
    for (int s = 0; s < len; s++) m = fmaxf(m, sc[tid][s]);
    float l = 0.f;
    for (int s = 0; s < len; s++) { float e = __expf(sc[tid][s] - m); sc[tid][s] = e; l += e; }
    wsum[tid] = 1.f / l;
  }
  __syncthreads();
  int k = tid >> 5, jl = tid & 31;
  for (int j = jl; j < 300; j += 32) {
    float a = 0.f;
    for (int s = 0; s < len; s++) a += sc[k][s] * bf2f(Vb[(size_t)(b * 128 + s) * 320 + j]);
    float val = a * wsum[k];
    size_t o = ((size_t)b * 8 + k) * 300 + j;
    if (is32) ((float*)dout)[o] = val;
    else ((u16*)dout)[o] = f2bf(val);
  }
}

extern "C" void kernel_launch(void* const* d_in, const int* in_sizes, int n_in,
                              void* d_out, int out_size, void* d_ws, size_t ws_size,
                              hipStream_t stream) {
  (void)in_sizes; (void)n_in; (void)out_size; (void)ws_size;
  const void* words = d_in[0];
  const int* lengths = (const int*)d_in[1];
  const void* vocab = d_in[2];
  const void* de = d_in[3];
  const void* W = d_in[4];
  const void* lWih = d_in[5];
  const void* lWhh = d_in[6];
  const void* lbih = d_in[7];
  const void* lbhh = d_in[8];
  const void* rWih = d_in[9];
  const void* rWhh = d_in[10];
  const void* rbih = d_in[11];
  const void* rbhh = d_in[12];

  char* basep = (char*)d_ws;
  size_t off = 0;
  auto take = [&](size_t bytes) -> char* {
    char* p = basep + off;
    off += (bytes + 255) & ~(size_t)255;
    return p;
  };
  // canonical bf16 inputs
  u16* cw    = (u16*)take(1228800 * 2);
  u16* cv    = (u16*)take(6000000 * 2);
  u16* cde   = (u16*)take(300 * 2);
  u16* cW    = (u16*)take(90000 * 2);
  u16* cWih  = (u16*)take(360000 * 2);
  u16* cWhh  = (u16*)take(360000 * 2);
  u16* cbih  = (u16*)take(1200 * 2);
  u16* cbhh  = (u16*)take(1200 * 2);
  u16* crWih = (u16*)take(90000 * 2);
  u16* crWhh = (u16*)take(90000 * 2);
  u16* crbih = (u16*)take(300 * 2);
  u16* crbhh = (u16*)take(300 * 2);
  u32* flag  = (u32*)take(256);
  // derived
  u16*   X     = (u16*)take((size_t)4096 * 320 * 2);
  u16*   Vb    = (u16*)take((size_t)4096 * 320 * 2);
  u16*   WihT  = (u16*)take((size_t)300 * 1200 * 2);
  u32*   W2    = (u32*)take((size_t)150 * 1200 * 4);
  u16*   rWihT = (u16*)take((size_t)300 * 300 * 2);
  u16*   rWhhT = (u16*)take((size_t)300 * 300 * 2);
  u16*   pAcc  = (u16*)take((size_t)8 * 4096 * 304 * 2);
  float* pML   = (float*)take((size_t)8 * 4096 * 2 * 4);
  float* H     = (float*)take((size_t)32 * 8 * 300 * 4);
  // union region: pA+pB (dead after k_softmax_v), then xg
  char* ureg = take((size_t)25000192);
  u16*   pA = (u16*)ureg;
  u16*   pB = (u16*)(ureg + (size_t)625 * 10240 * 2);
  float* xg = (float*)ureg;

  k_ingest<<<4096, 256, 0, stream>>>(words, vocab, de, W, lWih, lWhh, lbih, lbhh,
                                     rWih, rWhh, rbih, rbhh,
                                     cw, cv, cde, cW, cWih, cWhh, cbih, cbhh,
                                     crWih, crWhh, crbih, crbhh, flag);
  k_transpose_bf<<<dim3(38, 10), 256, 0, stream>>>(cWih, WihT, 1200, 300);
  k_transpose_bf<<<dim3(10, 10), 256, 0, stream>>>(crWih, rWihT, 300, 300);
  k_transpose_bf<<<dim3(10, 10), 256, 0, stream>>>(crWhh, rWhhT, 300, 300);
  k_pack_whh<<<(150 * 1200 + 255) / 256, 256, 0, stream>>>(cWhh, W2);
  k_pack_vocab<<<625, 256, 0, stream>>>(cv, pA, pB);
  k_xw<<<dim3(3, 128), 256, 0, stream>>>(cw, cW, X);
  k_softmax_v<<<256, 512, 0, stream>>>(X, pA, pB, pAcc, pML);
  k_combine<<<4096, 320, 0, stream>>>(pAcc, pML, X, cde, cw, Vb);
  k_xg<<<dim3(10, 128), 256, 0, stream>>>(Vb, WihT, cbih, cbhh, xg);
  k_lstm_rnn<<<32, 640, 0, stream>>>(xg, W2, rWihT, rWhhT, crbih, crbhh, lengths, H);
  k_attn<<<32, 256, 0, stream>>>(H, Vb, lengths, flag, d_out);
}

// Round 4
// 1082.279 us; speedup vs baseline: 1.2807x; 1.2807x over previous
//
#include <hip/hip_runtime.h>

// B=32, S=128, D=300 (pad 320), VOCAB=20000 (625 chunks of 32), K=8.
// Inputs may be f32 or bf16 (runtime-detected); canonicalized to bf16 in ws.

typedef unsigned short u16;
typedef unsigned int   u32;
typedef float  f32x4 __attribute__((ext_vector_type(4)));
typedef u32    u32x4 __attribute__((ext_vector_type(4)));
typedef __bf16 bf16x8 __attribute__((ext_vector_type(8)));
typedef _Float16 f16x2 __attribute__((ext_vector_type(2)));
typedef _Float16 f16x8 __attribute__((ext_vector_type(8)));

#define SCOPE_AGENT __HIP_MEMORY_SCOPE_AGENT

__device__ __forceinline__ float bf2f(u16 u) { return __uint_as_float(((u32)u) << 16); }
__device__ __forceinline__ u16 f2bf(float f) {
  u32 x = __float_as_uint(f);
  u32 r = (x + 0x7fffu + ((x >> 16) & 1u)) >> 16;  // RNE
  return (u16)r;
}
__device__ __forceinline__ float sigm(float x) { return 1.f / (1.f + __expf(-x)); }
__device__ __forceinline__ u16 f2h(float f) {
  union { _Float16 h; u16 u; } cv; cv.h = (_Float16)f; return cv.u;
}
__device__ __forceinline__ float h2f(u16 u) {
  union { _Float16 h; u16 u; } cv; cv.u = u; return (float)cv.h;
}

__device__ __forceinline__ f32x4 shflx4(f32x4 v, int m) {
  f32x4 r;
  r[0] = __shfl_xor(v[0], m, 16);
  r[1] = __shfl_xor(v[1], m, 16);
  r[2] = __shfl_xor(v[2], m, 16);
  r[3] = __shfl_xor(v[3], m, 16);
  return r;
}

// ---------- ingest: detect f32 vs bf16, canonicalize all float inputs to bf16 ----------
__device__ __forceinline__ void conv_seg(const void* src, u16* dst, int n, int is32,
                                         int t0, int stride) {
  if (is32) {
    const float* s = (const float*)src;
    for (int i = t0; i < n; i += stride) dst[i] = f2bf(s[i]);
  } else {
    const u16* s = (const u16*)src;
    for (int i = t0; i < n; i += stride) dst[i] = s[i];
  }
}

__global__ __launch_bounds__(256) void k_ingest(
    const void* words, const void* vocab, const void* de, const void* W,
    const void* lWih, const void* lWhh, const void* lbih, const void* lbhh,
    const void* rWih, const void* rWhh, const void* rbih, const void* rbhh,
    u16* cw, u16* cv, u16* cde, u16* cW, u16* cWih, u16* cWhh, u16* cbih, u16* cbhh,
    u16* crWih, u16* crWhh, u16* crbih, u16* crbhh, u32* flag, u32* seqz, u32* hbz) {
  __shared__ int s_is32;
  int tid = threadIdx.x;
  int vote = 0;
  if (tid < 64) {
    u32 w = ((const u32*)words)[tid];
    int e = (w >> 7) & 0xFF;  // bf16 low-element exponent field if bf16-packed
    vote = (e >= 100 && e <= 150) ? 1 : 0;
  }
  unsigned long long m = __ballot(vote);
  if (tid == 0) s_is32 = (__popcll(m) < 32) ? 1 : 0;  // few plausible bf16 exps -> f32
  __syncthreads();
  int is32 = s_is32;
  if (blockIdx.x == 0 && tid == 0) *flag = (u32)is32;
  int t0 = blockIdx.x * 256 + tid;
  int stride = gridDim.x * 256;
  if (t0 < 256) seqz[t0] = 0;     // LSTM step counters
  if (t0 < 10240) hbz[t0] = 0;    // LSTM h exchange buffers (f16 A-layout, both bufs)
  conv_seg(words, cw, 1228800, is32, t0, stride);
  conv_seg(vocab, cv, 6000000, is32, t0, stride);
  conv_seg(de, cde, 300, is32, t0, stride);
  conv_seg(W, cW, 90000, is32, t0, stride);
  conv_seg(lWih, cWih, 360000, is32, t0, stride);
  conv_seg(lWhh, cWhh, 360000, is32, t0, stride);
  conv_seg(lbih, cbih, 1200, is32, t0, stride);
  conv_seg(lbhh, cbhh, 1200, is32, t0, stride);
  conv_seg(rWih, crWih, 90000, is32, t0, stride);
  conv_seg(rWhh, crWhh, 90000, is32, t0, stride);
  conv_seg(rbih, crbih, 300, is32, t0, stride);
  conv_seg(rbhh, crbhh, 300, is32, t0, stride);
}

// ---------- transpose bf16 (J x K) -> bf16 (K x J) ----------
__global__ __launch_bounds__(256) void k_transpose_bf(const u16* __restrict__ in,
                                                      u16* __restrict__ out,
                                                      int J, int K) {
  __shared__ u16 t[32][33];
  int j0 = blockIdx.x * 32, k0 = blockIdx.y * 32;
  int lx = threadIdx.x & 31, ly = threadIdx.x >> 5;
  for (int r = ly; r < 32; r += 8) {
    int j = j0 + r, k = k0 + lx;
    t[r][lx] = (j < J && k < K) ? in[(size_t)j * K + k] : (u16)0;
  }
  __syncthreads();
  for (int r = ly; r < 32; r += 8) {
    int k = k0 + r, j = j0 + lx;
    if (k < K && j < J) out[(size_t)k * J + j] = t[lx][r];
  }
}

// ---------- pack lstm_Whh -> per-block MFMA B-frag slices (f16) ----------
// pW[bid=16][(nt*10+kt)*64+lane][8] f16; n = nt*16+(lane&15); gate=n/20; dl=n%20;
// dim = d0(bid)+dl; k = kt*32+(lane>>4)*8+j; val = Whh[gate*300+dim][k] (0 pad).
__global__ __launch_bounds__(256) void k_pack_w4(const u16* __restrict__ Whh,
                                                 u16* __restrict__ pW) {
  int idx = blockIdx.x * 256 + threadIdx.x;
  if (idx >= 16 * 25600) return;
  int bid = idx / 25600, r = idx % 25600;
  int t2 = r >> 9, lane = (r >> 3) & 63, j = r & 7;
  int nt = t2 / 10, kt = t2 % 10;
  int n = nt * 16 + (lane & 15);
  int gate = n / 20, dl = n % 20;
  int d0 = (bid < 15) ? 19 * bid : 285;
  int nd = (bid < 15) ? 19 : 15;
  int k = kt * 32 + ((lane >> 4) * 8) + j;
  u16 out = 0;
  if (dl < nd && k < 300) out = f2h(bf2f(Whh[(size_t)(gate * 300 + d0 + dl) * 300 + k]));
  pW[idx] = out;
}

// ---------- pack vocab into MFMA operand layouts ----------
__global__ __launch_bounds__(256) void k_pack_vocab(const u16* __restrict__ vocab,
                                                    u16* __restrict__ pA,
                                                    u16* __restrict__ pB) {
  __shared__ u16 sv[32][320];
  int ci = blockIdx.x, tid = threadIdx.x;
  for (int idx = tid; idx < 32 * 20; idx += 256) {
    int v = idx / 20, k = 300 + (idx - v * 20);
    sv[v][k] = 0;
  }
  for (int idx = tid; idx < 32 * 300; idx += 256) {
    int v = idx / 300, k = idx - v * 300;
    sv[v][k] = vocab[(size_t)(ci * 32 + v) * 300 + k];
  }
  __syncthreads();
  for (int idx = tid; idx < 10240; idx += 256) {
    int j = idx & 7, lane = (idx >> 3) & 63, t2 = idx >> 9;
    int kk = t2 % 10, h = t2 / 10;
    int v = h * 16 + (lane & 15);
    int k = kk * 32 + ((lane >> 4)) * 8 + j;
    pA[(size_t)ci * 10240 + (size_t)idx] = sv[v][k];
  }
  for (int idx = tid; idx < 9728; idx += 256) {
    int j = idx & 7, lane = (idx >> 3) & 63, nc = idx >> 9;
    int v = (lane >> 4) * 8 + j;
    int n = nc * 16 + (lane & 15);
    pB[(size_t)ci * 9728 + (size_t)idx] = sv[v][n];
  }
}

// ---------- X = words @ W -> bf16 (4096 x 320, zero pad) ----------
__global__ __launch_bounds__(256) void k_xw(const u16* __restrict__ words,
                                            const u16* __restrict__ W,
                                            u16* __restrict__ X) {
  __shared__ float As[300][33];
  int n0 = blockIdx.x * 128;
  int r0 = blockIdx.y * 32;
  int tid = threadIdx.x;
  for (int idx = tid; idx < 32 * 300; idx += 256) {
    int r = idx / 300, k = idx - r * 300;
    As[k][r] = bf2f(words[(size_t)(r0 + r) * 300 + k]);
  }
  __syncthreads();
  int j = n0 + (tid & 127);
  int rh = (tid >> 7) * 16;
  float acc[16];
#pragma unroll
  for (int i = 0; i < 16; i++) acc[i] = 0.f;
  if (j < 300) {
    for (int k = 0; k < 300; k++) {
      float bw = bf2f(W[(size_t)k * 300 + j]);
#pragma unroll
      for (int i = 0; i < 16; i++) acc[i] += As[k][rh + i] * bw;
    }
  }
  if (j < 320) {
#pragma unroll
    for (int i = 0; i < 16; i++) {
      float v = (j < 300) ? acc[i] : 0.f;
      X[(size_t)(r0 + rh + i) * 320 + j] = f2bf(v);
    }
  }
}

// ---------- flash-style softmax-weighted vocab sum (MFMA), per-slice partials ----------
__global__ __launch_bounds__(512, 2) void k_softmax_v(
    const u16* __restrict__ X, const u16* __restrict__ pA, const u16* __restrict__ pB,
    u16* __restrict__ pAcc, float* __restrict__ pML) {
  __shared__ __align__(16) u16 chunk[19968];
  __shared__ __align__(16) float ptbuf[8 * 576];
  int bid = blockIdx.x;
  int sl = bid & 7, b = bid >> 3;
  int tid = threadIdx.x;
  int w = tid >> 6, lane = tid & 63;
  int quad = lane >> 4, n16 = lane & 15;
  int cs = (sl == 0) ? 0 : 79 + (sl - 1) * 78;
  int nch = (sl == 0) ? 79 : 78;

  int rowA = b * 128 + w * 16 + n16;
  const bf16x8* Xrow = (const bf16x8*)(X + (size_t)rowA * 320);
  bf16x8 afr[10];
#pragma unroll
  for (int kk = 0; kk < 10; kk++) afr[kk] = Xrow[kk * 4 + quad];

  f32x4 acc[19];
#pragma unroll
  for (int i = 0; i < 19; i++) { acc[i][0] = 0.f; acc[i][1] = 0.f; acc[i][2] = 0.f; acc[i][3] = 0.f; }
  f32x4 mrun, lrun;
#pragma unroll
  for (int c = 0; c < 4; c++) { mrun[c] = -1e30f; lrun[c] = 0.f; }
  float* myPt = ptbuf + w * 576;

  {
    const u32x4* gA = (const u32x4*)pA + (size_t)cs * 1280;
    const u32x4* gB = (const u32x4*)pB + (size_t)cs * 1216;
    u32x4* sb = (u32x4*)&chunk[0];
    for (int idx = tid; idx < 2496; idx += 512)
      sb[idx] = (idx < 1280) ? gA[idx] : gB[idx - 1280];
  }
  __syncthreads();

  for (int ic = 0; ic < nch; ic++) {
    u32x4 pf[5];
    bool havepf = (ic + 1 < nch);
    if (havepf) {
      int ci = cs + ic + 1;
      const u32x4* gA = (const u32x4*)pA + (size_t)ci * 1280;
      const u32x4* gB = (const u32x4*)pB + (size_t)ci * 1216;
#pragma unroll
      for (int i = 0; i < 5; i++) {
        int idx = tid + i * 512;
        if (idx < 2496) pf[i] = (idx < 1280) ? gA[idx] : gB[idx - 1280];
      }
    }
    const bf16x8* bufA = (const bf16x8*)&chunk[0];
    const bf16x8* bufB = (const bf16x8*)&chunk[10240];
    f32x4 L0, L1;
#pragma unroll
    for (int c = 0; c < 4; c++) { L0[c] = 0.f; L1[c] = 0.f; }
#pragma unroll
    for (int kk = 0; kk < 10; kk++) {
      L0 = __builtin_amdgcn_mfma_f32_16x16x32_bf16(afr[kk], bufA[kk * 64 + lane], L0, 0, 0, 0);
      L1 = __builtin_amdgcn_mfma_f32_16x16x32_bf16(afr[kk], bufA[(10 + kk) * 64 + lane], L1, 0, 0, 0);
    }
    f32x4 t;
#pragma unroll
    for (int c = 0; c < 4; c++) t[c] = fmaxf(L0[c], L1[c]);
#pragma unroll
    for (int off = 1; off < 16; off <<= 1) {
      f32x4 o = shflx4(t, off);
#pragma unroll
      for (int c = 0; c < 4; c++) t[c] = fmaxf(t[c], o[c]);
    }
    f32x4 mnew, al, P0v, P1v, rs;
#pragma unroll
    for (int c = 0; c < 4; c++) {
      mnew[c] = fmaxf(mrun[c], t[c]);
      al[c] = __expf(mrun[c] - mnew[c]);
      P0v[c] = __expf(L0[c] - mnew[c]);
      P1v[c] = __expf(L1[c] - mnew[c]);
      rs[c] = P0v[c] + P1v[c];
    }
#pragma unroll
    for (int off = 1; off < 16; off <<= 1) {
      f32x4 o = shflx4(rs, off);
#pragma unroll
      for (int c = 0; c < 4; c++) rs[c] += o[c];
    }
#pragma unroll
    for (int c = 0; c < 4; c++) { lrun[c] = lrun[c] * al[c] + rs[c]; mrun[c] = mnew[c]; }
#pragma unroll
    for (int r = 0; r < 4; r++) {
      myPt[(quad * 4 + r) * 36 + n16] = P0v[r];
      myPt[(quad * 4 + r) * 36 + 16 + n16] = P1v[r];
    }
    __syncthreads();
    f32x4 plo = *(const f32x4*)(myPt + n16 * 36 + quad * 8);
    f32x4 phi = *(const f32x4*)(myPt + n16 * 36 + quad * 8 + 4);
    bf16x8 paf;
#pragma unroll
    for (int c = 0; c < 4; c++) { paf[c] = (__bf16)plo[c]; paf[c + 4] = (__bf16)phi[c]; }
#pragma unroll
    for (int nc = 0; nc < 19; nc++) {
      f32x4 a = acc[nc];
#pragma unroll
      for (int c = 0; c < 4; c++) a[c] *= al[c];
      acc[nc] = __builtin_amdgcn_mfma_f32_16x16x32_bf16(paf, bufB[nc * 64 + lane], a, 0, 0, 0);
    }
    __syncthreads();
    if (havepf) {
      u32x4* sb = (u32x4*)&chunk[0];
#pragma unroll
      for (int i = 0; i < 5; i++) {
        int idx = tid + i * 512;
        if (idx < 2496) sb[idx] = pf[i];
      }
    }
    __syncthreads();
  }

  size_t prow = (size_t)sl * 4096 + (size_t)b * 128 + w * 16;
  if (n16 == 0) {
#pragma unroll
    for (int r = 0; r < 4; r++) {
      pML[(prow + quad * 4 + r) * 2 + 0] = mrun[r];
      pML[(prow + quad * 4 + r) * 2 + 1] = lrun[r];
    }
  }
#pragma unroll
  for (int nc = 0; nc < 19; nc++)
#pragma unroll
    for (int r = 0; r < 4; r++)
      pAcc[(prow + quad * 4 + r) * 304 + nc * 16 + n16] = f2bf(acc[nc][r]);
}

// ---------- combine slices + default-embed column -> V bf16 (4096 x 320) ----------
__global__ __launch_bounds__(320) void k_combine(
    const u16* __restrict__ pAcc, const float* __restrict__ pML,
    const u16* __restrict__ X, const u16* __restrict__ de,
    const u16* __restrict__ words, u16* __restrict__ Vout) {
  __shared__ float red[320];
  __shared__ float fs[8];
  __shared__ float sinv, sw;
  int row = blockIdx.x, tid = threadIdx.x;
  float p = 0.f;
  if (tid < 300) p = bf2f(X[(size_t)row * 320 + tid]) * bf2f(de[tid]);
  red[tid] = p;
  __syncthreads();
  if (tid == 0) {
    float d = 0.f;
    for (int i = 0; i < 300; i++) d += red[i];
    float mv[8], lv[8], ms = -1e30f;
    for (int s = 0; s < 8; s++) {
      mv[s] = pML[((size_t)s * 4096 + row) * 2];
      lv[s] = pML[((size_t)s * 4096 + row) * 2 + 1];
      ms = fmaxf(ms, mv[s]);
    }
    float mf = fmaxf(ms, d);
    float pd = __expf(d - mf);
    float l = pd;
    for (int s = 0; s < 8; s++) {
      float f = __expf(mv[s] - mf);
      fs[s] = f;
      l += lv[s] * f;
    }
    sinv = 1.f / l;
    sw = pd / l;
  }
  __syncthreads();
  float v = 0.f;
  if (tid < 300) {
    float a = 0.f;
#pragma unroll
    for (int s = 0; s < 8; s++)
      a += bf2f(pAcc[((size_t)s * 4096 + row) * 304 + tid]) * fs[s];
    v = a * sinv + sw * bf2f(words[(size_t)row * 300 + tid]);
  }
  Vout[(size_t)row * 320 + tid] = f2bf(v);
}

// ---------- xg = V @ lstm_Wih.T + bih + bhh (f32, 4096 x 1200) ----------
__global__ __launch_bounds__(256) void k_xg(const u16* __restrict__ Vb,
                                            const u16* __restrict__ WihT,
                                            const u16* __restrict__ bih,
                                            const u16* __restrict__ bhh,
                                            float* __restrict__ xg) {
  __shared__ float As[300][33];
  int n0 = blockIdx.x * 128;
  int r0 = blockIdx.y * 32;
  int tid = threadIdx.x;
  for (int idx = tid; idx < 32 * 300; idx += 256) {
    int r = idx / 300, k = idx - r * 300;
    As[k][r] = bf2f(Vb[(size_t)(r0 + r) * 320 + k]);
  }
  __syncthreads();
  int j = n0 + (tid & 127);
  if (j >= 1200) return;
  int rh = (tid >> 7) * 16;
  float acc[16];
#pragma unroll
  for (int i = 0; i < 16; i++) acc[i] = 0.f;
  for (int k = 0; k < 300; k++) {
    float bw = bf2f(WihT[(size_t)k * 1200 + j]);
#pragma unroll
    for (int i = 0; i < 16; i++) acc[i] += As[k][rh + i] * bw;
  }
  float bias = bf2f(bih[j]) + bf2f(bhh[j]);
#pragma unroll
  for (int i = 0; i < 16; i++)
    xg[(size_t)(r0 + rh + i) * 1200 + j] = acc[i] + bias;
}

// ---------- lockstep LSTM: 16 blocks, MFMA f16, weights in registers ----------
// Block bid owns dims [d0, d0+nd) x 4 gates (N=80 cols padded). Per step:
// spin(16 seq, acquire) -> load h A-frags (global, f16 A-layout, dbuf) ->
// 20 MFMA/wave -> gl LDS -> activations (c,h in regs) -> publish h slice ->
// barrier -> release seq. h_t for all 32 batches lives in hb[(t+1)&1].
__global__ __launch_bounds__(320, 1) void k_lstm2(
    const float* __restrict__ xg, const u16* __restrict__ pW,
    const int* __restrict__ lengths, u16* __restrict__ hb, u32* __restrict__ seq) {
  __shared__ float gl[32][84];
  __shared__ int s_maxlen;
  int bid = blockIdx.x, tid = threadIdx.x;
  int w = tid >> 6, lane = tid & 63;
  int quad = lane >> 4, n16 = lane & 15;
  int d0 = (bid < 15) ? 19 * bid : 285;
  int nd = (bid < 15) ? 19 : 15;
  {
    int lv = (tid < 32) ? lengths[tid] : 0;
    for (int off2 = 1; off2 < 32; off2 <<= 1) {
      int o = __shfl_xor(lv, off2, 64);
      lv = lv > o ? lv : o;
    }
    if (tid == 0) s_maxlen = lv;
  }
  // B-frags: constant across steps, in registers (wave w = N-tile)
  f16x8 bf[10];
  const u32x4* pw4 = (const u32x4*)(pW + (size_t)bid * 25600);
#pragma unroll
  for (int kt = 0; kt < 10; kt++)
    bf[kt] = __builtin_bit_cast(f16x8, pw4[(w * 10 + kt) * 64 + lane]);
  // activation-thread ownership: items tid and tid+320; item = b*20+dl
  int b0 = tid / 20, dl0 = tid - b0 * 20;
  int b1 = (tid + 320) / 20, dl1 = (tid + 320) - b1 * 20;
  bool a0 = dl0 < nd, a1 = dl1 < nd;
  int len0 = lengths[b0], len1 = lengths[b1];
  int dim0 = d0 + dl0, dim1 = d0 + dl1;
  int sa0 = (((b0 >> 4) * 10 + (dim0 >> 5)) * 64 + ((dim0 >> 3) & 3) * 16 + (b0 & 15)) * 8 + (dim0 & 7);
  int sa1 = (((b1 >> 4) * 10 + (dim1 >> 5)) * 64 + ((dim1 >> 3) & 3) * 16 + (b1 & 15)) * 8 + (dim1 & 7);
  float c0 = 0.f, h0 = 0.f, c1 = 0.f, h1 = 0.f;
  __syncthreads();
  int maxlen = s_maxlen;
  for (int t = 0; t < maxlen; t++) {
    if (tid < 16) {
      while (__hip_atomic_load(&seq[tid * 16], __ATOMIC_ACQUIRE, SCOPE_AGENT) < (u32)t)
        __builtin_amdgcn_s_sleep(2);
    }
    __syncthreads();
    // xv loads (independent of h; overlap with A-frag latency)
    float xv00 = 0.f, xv01 = 0.f, xv02 = 0.f, xv03 = 0.f;
    float xv10 = 0.f, xv11 = 0.f, xv12 = 0.f, xv13 = 0.f;
    const float* xr0 = xg + ((size_t)b0 * 128 + t) * 1200 + dim0;
    const float* xr1 = xg + ((size_t)b1 * 128 + t) * 1200 + dim1;
    if (a0) { xv00 = xr0[0]; xv01 = xr0[300]; xv02 = xr0[600]; xv03 = xr0[900]; }
    if (a1) { xv10 = xr1[0]; xv11 = xr1[300]; xv12 = xr1[600]; xv13 = xr1[900]; }
    // A-frags: h_{t-1} for all 32 batches, f16 A-layout
    const u32x4* hbt = (const u32x4*)hb + (size_t)(t & 1) * 1280;
    u32x4 af[2][10];
#pragma unroll
    for (int mt = 0; mt < 2; mt++)
#pragma unroll
      for (int kt = 0; kt < 10; kt++)
        af[mt][kt] = hbt[(mt * 10 + kt) * 64 + lane];
#pragma unroll
    for (int mt = 0; mt < 2; mt++) {
      f32x4 C;
      C[0] = 0.f; C[1] = 0.f; C[2] = 0.f; C[3] = 0.f;
#pragma unroll
      for (int kt = 0; kt < 10; kt++)
        C = __builtin_amdgcn_mfma_f32_16x16x32_f16(
            __builtin_bit_cast(f16x8, af[mt][kt]), bf[kt], C, 0, 0, 0);
#pragma unroll
      for (int rr = 0; rr < 4; rr++)
        gl[mt * 16 + quad * 4 + rr][w * 16 + n16] = C[rr];
    }
    __syncthreads();
    u16* hbw = hb + (size_t)((t + 1) & 1) * 10240;
    if (a0) {
      float gi = gl[b0][dl0] + xv00, gf = gl[b0][20 + dl0] + xv01;
      float gg = gl[b0][40 + dl0] + xv02, go = gl[b0][60 + dl0] + xv03;
      if (t < len0) {
        c0 = sigm(gf) * c0 + sigm(gi) * tanhf(gg);
        h0 = sigm(go) * tanhf(c0);
      }
      hbw[sa0] = f2h(h0);
    }
    if (a1) {
      float gi = gl[b1][dl1] + xv10, gf = gl[b1][20 + dl1] + xv11;
      float gg = gl[b1][40 + dl1] + xv12, go = gl[b1][60 + dl1] + xv13;
      if (t < len1) {
        c1 = sigm(gf) * c1 + sigm(gi) * tanhf(gg);
        h1 = sigm(go) * tanhf(c1);
      }
      hbw[sa1] = f2h(h1);
    }
    __syncthreads();  // drains vmem stores (vmcnt) block-wide before release
    if (tid == 0)
      __hip_atomic_store(&seq[bid * 16], (u32)(t + 1), __ATOMIC_RELEASE, SCOPE_AGENT);
  }
}

// ---------- RNN tail: q from hb (f16 A-layout), 8 steps h2 = tanh(base + h2@rWhh.T) ----------
__global__ __launch_bounds__(320) void k_rnn(
    const u16* __restrict__ hb, const int* __restrict__ lengths,
    const u16* __restrict__ rWihT, const u16* __restrict__ rWhhT,
    const u16* __restrict__ rbih, const u16* __restrict__ rbhh,
    float* __restrict__ H) {
  __shared__ float qs[304], h2[304], base[304];
  __shared__ int s_maxlen;
  int b = blockIdx.x, tid = threadIdx.x;
  {
    int lv = (tid < 32) ? lengths[tid] : 0;
    for (int off2 = 1; off2 < 32; off2 <<= 1) {
      int o = __shfl_xor(lv, off2, 64);
      lv = lv > o ? lv : o;
    }
    if (tid == 0) s_maxlen = lv;
  }
  __syncthreads();
  int buf = s_maxlen & 1;
  if (tid < 304) {
    float q = 0.f;
    if (tid < 300) {
      int dim = tid;
      int idx = (((b >> 4) * 10 + (dim >> 5)) * 64 + ((dim >> 3) & 3) * 16 + (b & 15)) * 8 + (dim & 7);
      q = h2f(hb[(size_t)buf * 10240 + idx]);
    }
    qs[tid] = q;
    h2[tid] = 0.f;
  }
  __syncthreads();
  if (tid < 300) {
    float a = bf2f(rbih[tid]) + bf2f(rbhh[tid]);
    for (int k = 0; k < 300; k++) a += qs[k] * bf2f(rWihT[(size_t)k * 300 + tid]);
    base[tid] = a;
  }
  __syncthreads();
  for (int s = 0; s < 8; s++) {
    float nv = 0.f;
    if (tid < 300) {
      float a = base[tid];
      for (int k = 0; k < 300; k++) a += h2[k] * bf2f(rWhhT[(size_t)k * 300 + tid]);
      nv = tanhf(a);
    }
    __syncthreads();
    if (tid < 300) {
      h2[tid] = nv;
      H[((size_t)b * 8 + s) * 300 + tid] = nv;
    }
    __syncthreads();
  }
}

// ---------- attention readout ----------
__global__ __launch_bounds__(256) void k_attn(const float* __restrict__ H,
                                              const u16* __restrict__ Vb,
                                              const int* __restrict__ lengths,
                                              const u32* __restrict__ flag,
                                              void* __restrict__ dout) {
  __shared__ float Hs[8][304];
  __shared__ float sc[8][128];
  __shared__ float wsum[8];
  int b = blockIdx.x, tid = threadIdx.x;
  int len = lengths[b];
  int is32 = (int)*flag;
  for (int idx = tid; idx < 8 * 300; idx += 256) {
    int k = idx / 300, j = idx - k * 300;
    Hs[k][j] = H[((size_t)b * 8 + k) * 300 + j];
  }
  __syncthreads();
  for (int s = tid; s < len; s += 256) {
    const u16* vr = Vb + (size_t)(b * 128 + s) * 320;
    float a[8];
#pragma unroll
    for (int k = 0; k < 8; k++) a[k] = 0.f;
    for (int j = 0; j < 300; j++) {
      float v = bf2f(vr[j]);
#pragma unroll
      for (int k = 0; k < 8; k++) a[k] += Hs[k][j] * v;
    }
#pragma unroll
    for (int k = 0; k < 8; k++) sc[k][s] = a[k];
  }
  __syncthreads();
  if (tid < 8) {
    float m = -1e30f;
    for (int s = 0; s < len; s++) m = fmaxf(m, sc[tid][s]);
    float l = 0.f;
    for (int s = 0; s < len; s++) { float e = __expf(sc[tid][s] - m); sc[tid][s] = e; l += e; }
    wsum[tid] = 1.f / l;
  }
  __syncthreads();
  int k = tid >> 5, jl = tid & 31;
  for (int j = jl; j < 300; j += 32) {
    float a = 0.f;
    for (int s = 0; s < len; s++) a += sc[k][s] * bf2f(Vb[(size_t)(b * 128 + s) * 320 + j]);
    float val = a * wsum[k];
    size_t o = ((size_t)b * 8 + k) * 300 + j;
    if (is32) ((float*)dout)[o] = val;
    else ((u16*)dout)[o] = f2bf(val);
  }
}

extern "C" void kernel_launch(void* const* d_in, const int* in_sizes, int n_in,
                              void* d_out, int out_size, void* d_ws, size_t ws_size,
                              hipStream_t stream) {
  (void)in_sizes; (void)n_in; (void)out_size; (void)ws_size;
  const void* words = d_in[0];
  const int* lengths = (const int*)d_in[1];
  const void* vocab = d_in[2];
  const void* de = d_in[3];
  const void* W = d_in[4];
  const void* lWih = d_in[5];
  const void* lWhh = d_in[6];
  const void* lbih = d_in[7];
  const void* lbhh = d_in[8];
  const void* rWih = d_in[9];
  const void* rWhh = d_in[10];
  const void* rbih = d_in[11];
  const void* rbhh = d_in[12];

  char* basep = (char*)d_ws;
  size_t off = 0;
  auto take = [&](size_t bytes) -> char* {
    char* p = basep + off;
    off += (bytes + 255) & ~(size_t)255;
    return p;
  };
  u16* cw    = (u16*)take(1228800 * 2);
  u16* cv    = (u16*)take(6000000 * 2);
  u16* cde   = (u16*)take(300 * 2);
  u16* cW    = (u16*)take(90000 * 2);
  u16* cWih  = (u16*)take(360000 * 2);
  u16* cWhh  = (u16*)take(360000 * 2);
  u16* cbih  = (u16*)take(1200 * 2);
  u16* cbhh  = (u16*)take(1200 * 2);
  u16* crWih = (u16*)take(90000 * 2);
  u16* crWhh = (u16*)take(90000 * 2);
  u16* crbih = (u16*)take(300 * 2);
  u16* crbhh = (u16*)take(300 * 2);
  u32* flag  = (u32*)take(256);
  u16*   X     = (u16*)take((size_t)4096 * 320 * 2);
  u16*   Vb    = (u16*)take((size_t)4096 * 320 * 2);
  u16*   WihT  = (u16*)take((size_t)300 * 1200 * 2);
  u16*   pW4   = (u16*)take((size_t)16 * 25600 * 2);
  u16*   rWihT = (u16*)take((size_t)300 * 300 * 2);
  u16*   rWhhT = (u16*)take((size_t)300 * 300 * 2);
  u16*   pAcc  = (u16*)take((size_t)8 * 4096 * 304 * 2);
  float* pML   = (float*)take((size_t)8 * 4096 * 2 * 4);
  float* H     = (float*)take((size_t)32 * 8 * 300 * 4);
  u16*   hb    = (u16*)take((size_t)2 * 10240 * 2);
  u32*   seq   = (u32*)take((size_t)4096 * 4);
  // union region: pA+pB (dead after k_softmax_v), then xg
  char* ureg = take((size_t)25000192);
  u16*   pA = (u16*)ureg;
  u16*   pB = (u16*)(ureg + (size_t)625 * 10240 * 2);
  float* xg = (float*)ureg;

  k_ingest<<<4096, 256, 0, stream>>>(words, vocab, de, W, lWih, lWhh, lbih, lbhh,
                                     rWih, rWhh, rbih, rbhh,
                                     cw, cv, cde, cW, cWih, cWhh, cbih, cbhh,
                                     crWih, crWhh, crbih, crbhh, flag, seq, (u32*)hb);
  k_transpose_bf<<<dim3(38, 10), 256, 0, stream>>>(cWih, WihT, 1200, 300);
  k_transpose_bf<<<dim3(10, 10), 256, 0, stream>>>(crWih, rWihT, 300, 300);
  k_transpose_bf<<<dim3(10, 10), 256, 0, stream>>>(crWhh, rWhhT, 300, 300);
  k_pack_w4<<<1600, 256, 0, stream>>>(cWhh, pW4);
  k_pack_vocab<<<625, 256, 0, stream>>>(cv, pA, pB);
  k_xw<<<dim3(3, 128), 256, 0, stream>>>(cw, cW, X);
  k_softmax_v<<<256, 512, 0, stream>>>(X, pA, pB, pAcc, pML);
  k_combine<<<4096, 320, 0, stream>>>(pAcc, pML, X, cde, cw, Vb);
  k_xg<<<dim3(10, 128), 256, 0, stream>>>(Vb, WihT, cbih, cbhh, xg);
  k_lstm2<<<16, 320, 0, stream>>>(xg, pW4, lengths, hb, seq);
  k_rnn<<<32, 320, 0, stream>>>(hb, lengths, rWihT, rWhhT, crbih, crbhh, H);
  k_attn<<<32, 256, 0, stream>>>(H, Vb, lengths, flag, d_out);
}